// Round 2
// baseline (527.100 us; speedup 1.0000x reference)
//
#include <hip/hip_runtime.h>
#include <math.h>

// NeighborlistVerletNsq: N=4096 particles, P = N(N-1)/2 pairs.
// Outputs (flattened float32, in return order):
//   [0      , 4P ) pairs   [2,2P] row-major: row0 = concat(i,j), row1 = concat(j,i)
//   [4P     , 6P ) d_full  [2P,1]: concat(d_m, d_m)
//   [6P     , 12P) r_full  [2P,3] row-major: concat(r_m, -r_m)
//   [12P    , 14P) mask    [2P]: concat(mask, mask) as 0/1
//
// R1: 4 pairs/thread, all-float4 stores (r_full region becomes 3 contiguous
// dwordx4 per quad instead of 6 stride-12 scalar stores). Numerics unchanged
// (exact numpy match: fmodf + sign fixup, no-fma norm).

#define CUTOFF_F 0.5f

__device__ __forceinline__ float pbc_wrap(float r, float L, float h) {
    float t = __fadd_rn(r, h);         // r + half
    float m = fmodf(t, L);             // exact, sign of dividend (numpy fmod)
    if (m < 0.0f) m = __fadd_rn(m, L); // numpy remainder sign fixup (L > 0)
    return __fsub_rn(m, h);            // - half
}

__device__ __forceinline__ void compute_pair(const float* __restrict__ pos,
                                             float Lx, float Ly, float Lz,
                                             float hx, float hy, float hz,
                                             int i, int j,
                                             float& fi, float& fj, float& dm,
                                             float& mx, float& my, float& mz,
                                             float& mk) {
    float rx = __fsub_rn(pos[3 * i + 0], pos[3 * j + 0]);
    float ry = __fsub_rn(pos[3 * i + 1], pos[3 * j + 1]);
    float rz = __fsub_rn(pos[3 * i + 2], pos[3 * j + 2]);

    rx = pbc_wrap(rx, Lx, hx);
    ry = pbc_wrap(ry, Ly, hy);
    rz = pbc_wrap(rz, Lz, hz);

    // no-fma norm: ((x*x + y*y) + z*z), each op rounded fp32
    float d2 = __fadd_rn(__fadd_rn(__fmul_rn(rx, rx), __fmul_rn(ry, ry)),
                         __fmul_rn(rz, rz));
    float d = sqrtf(d2);

    const bool keep = (d <= CUTOFF_F);
    dm = keep ? d  : 0.0f;
    mx = keep ? rx : 0.0f;
    my = keep ? ry : 0.0f;
    mz = keep ? rz : 0.0f;
    mk = keep ? 1.0f : 0.0f;
    fi = (float)i;
    fj = (float)j;
}

__global__ __launch_bounds__(256)
void nl_nsq_kernel4(const float* __restrict__ pos,
                    const float* __restrict__ box,
                    const int*   __restrict__ ip,
                    const int*   __restrict__ jp,
                    float*       __restrict__ out,
                    long long P) {
    const long long q = (long long)blockIdx.x * blockDim.x + threadIdx.x; // quad idx
    const long long p = 4 * q;
    if (p >= P) return;

    const float Lx = box[0], Ly = box[4], Lz = box[8];
    const float hx = Lx * 0.5f, hy = Ly * 0.5f, hz = Lz * 0.5f;

    if (p + 3 < P) {
        // vector path: 4 pairs, float4 loads/stores
        const int4 iv = ((const int4*)ip)[q];
        const int4 jv = ((const int4*)jp)[q];
        const int ia[4] = {iv.x, iv.y, iv.z, iv.w};
        const int ja[4] = {jv.x, jv.y, jv.z, jv.w};

        float fi[4], fj[4], dm[4], mx[4], my[4], mz[4], mk[4];
#pragma unroll
        for (int k = 0; k < 4; ++k) {
            compute_pair(pos, Lx, Ly, Lz, hx, hy, hz, ia[k], ja[k],
                         fi[k], fj[k], dm[k], mx[k], my[k], mz[k], mk[k]);
        }

        float4* o = (float4*)out;
        const long long P4 = P >> 2;   // P divisible by 4 on the vector path bases

        const float4 vfi = make_float4(fi[0], fi[1], fi[2], fi[3]);
        const float4 vfj = make_float4(fj[0], fj[1], fj[2], fj[3]);
        const float4 vdm = make_float4(dm[0], dm[1], dm[2], dm[3]);
        const float4 vmk = make_float4(mk[0], mk[1], mk[2], mk[3]);

        // pairs [2,2P]
        o[q]           = vfi;
        o[P4 + q]      = vfj;
        o[2 * P4 + q]  = vfj;
        o[3 * P4 + q]  = vfi;
        // d_full [2P]
        o[4 * P4 + q]  = vdm;
        o[5 * P4 + q]  = vdm;
        // r_full [2P,3]: 12 floats = 3 float4 per quad, contiguous
        {
            const long long b0 = 6 * P4 + 3 * q;
            o[b0 + 0] = make_float4(mx[0], my[0], mz[0], mx[1]);
            o[b0 + 1] = make_float4(my[1], mz[1], mx[2], my[2]);
            o[b0 + 2] = make_float4(mz[2], mx[3], my[3], mz[3]);
            const long long b1 = 9 * P4 + 3 * q;
            o[b1 + 0] = make_float4(-mx[0], -my[0], -mz[0], -mx[1]);
            o[b1 + 1] = make_float4(-my[1], -mz[1], -mx[2], -my[2]);
            o[b1 + 2] = make_float4(-mz[2], -mx[3], -my[3], -mz[3]);
        }
        // mask_full [2P]
        o[12 * P4 + q] = vmk;
        o[13 * P4 + q] = vmk;
    } else {
        // scalar tail (unused when P % 4 == 0, kept for generality)
        for (long long pp = p; pp < P; ++pp) {
            float fi, fj, dm, mx, my, mz, mk;
            compute_pair(pos, Lx, Ly, Lz, hx, hy, hz, ip[pp], jp[pp],
                         fi, fj, dm, mx, my, mz, mk);
            out[pp]          = fi;
            out[P + pp]      = fj;
            out[2 * P + pp]  = fj;
            out[3 * P + pp]  = fi;
            out[4 * P + pp]  = dm;
            out[5 * P + pp]  = dm;
            long long b0 = 6 * P + 3 * pp;
            out[b0 + 0] = mx;  out[b0 + 1] = my;  out[b0 + 2] = mz;
            long long b1 = 6 * P + 3 * (P + pp);
            out[b1 + 0] = -mx; out[b1 + 1] = -my; out[b1 + 2] = -mz;
            out[12 * P + pp] = mk;
            out[13 * P + pp] = mk;
        }
    }
}

extern "C" void kernel_launch(void* const* d_in, const int* in_sizes, int n_in,
                              void* d_out, int out_size, void* d_ws, size_t ws_size,
                              hipStream_t stream) {
    const float* pos = (const float*)d_in[0];  // [N,3]
    const float* box = (const float*)d_in[1];  // [3,3]
    const int*   ip  = (const int*)d_in[2];    // [P]
    const int*   jp  = (const int*)d_in[3];    // [P]
    float*       out = (float*)d_out;

    const long long P = (long long)in_sizes[2];
    const long long nq = (P + 3) / 4;

    const int block = 256;
    const long long grid = (nq + block - 1) / block;
    nl_nsq_kernel4<<<(dim3)(unsigned)grid, block, 0, stream>>>(pos, box, ip, jp, out, P);
}

// Round 4
// 512.750 us; speedup vs baseline: 1.0280x; 1.0280x over previous
//
#include <hip/hip_runtime.h>
#include <math.h>

// NeighborlistVerletNsq: N=4096 particles, P = N(N-1)/2 pairs.
// Outputs (flattened float32, in return order):
//   [0   , 4P ) pairs  [2,2P]: row0 = concat(i,j), row1 = concat(j,i)
//   [4P  , 6P ) d_full [2P,1]: concat(d_m, d_m)
//   [6P  , 12P) r_full [2P,3]: concat(r_m, -r_m), row-major
//   [12P , 14P) mask   [2P]  : concat(mask, mask) as 0/1
//
// R4 = R3 with the nontemporal builtin fixed (clang ext_vector_type instead
// of HIP float4 struct). R3 changes recap:
//  * fmodf eliminated: t = r+half ∈ (-L, 2L), so numpy remainder(t,L) ==
//    (t>=L ? t-L : (t<0 ? t+L : t)). t-L is Sterbenz-exact (== exact fmod);
//    t+L is the same single-rounded add numpy's fixup does. Bit-identical.
//  * block-strided pair mapping (p = base + t + 256*s): every scalar-region
//    store is lane-contiguous (coalesced).
//  * r_full staged in LDS (stride-3 scalar writes: 3 coprime 32 -> no bank
//    conflicts), then written out as lane-contiguous float4 for +r and -r.
//  * nontemporal stores (output never re-read).

#define CUTOFF_F 0.5f
#define BLOCK 256
#define SPT 4                          // pairs per thread
#define PPB (BLOCK * SPT)              // 1024 pairs per block

typedef float fx4 __attribute__((ext_vector_type(4)));

__device__ __forceinline__ float pbc_wrap_fast(float r, float L, float h) {
    float t = __fadd_rn(r, h);                 // r + half (same rounding as ref)
    float m = (t >= L) ? __fsub_rn(t, L)       // exact fmod for t in [L,2L)
            : (t < 0.0f ? __fadd_rn(t, L)      // numpy sign fixup, one rounding
                        : t);
    return __fsub_rn(m, h);                    // - half
}

__device__ __forceinline__ void compute_pair(const float* __restrict__ pos,
                                             float Lx, float Ly, float Lz,
                                             float hx, float hy, float hz,
                                             int i, int j,
                                             float& fi, float& fj, float& dm,
                                             float& mx, float& my, float& mz,
                                             float& mk) {
    float rx = __fsub_rn(pos[3 * i + 0], pos[3 * j + 0]);
    float ry = __fsub_rn(pos[3 * i + 1], pos[3 * j + 1]);
    float rz = __fsub_rn(pos[3 * i + 2], pos[3 * j + 2]);

    rx = pbc_wrap_fast(rx, Lx, hx);
    ry = pbc_wrap_fast(ry, Ly, hy);
    rz = pbc_wrap_fast(rz, Lz, hz);

    // no-fma norm: ((x*x + y*y) + z*z), each op rounded fp32
    float d2 = __fadd_rn(__fadd_rn(__fmul_rn(rx, rx), __fmul_rn(ry, ry)),
                         __fmul_rn(rz, rz));
    float d = sqrtf(d2);

    const bool keep = (d <= CUTOFF_F);
    dm = keep ? d  : 0.0f;
    mx = keep ? rx : 0.0f;
    my = keep ? ry : 0.0f;
    mz = keep ? rz : 0.0f;
    mk = keep ? 1.0f : 0.0f;
    fi = (float)i;
    fj = (float)j;
}

__device__ __forceinline__ void nt_store(float* p, float v) {
    __builtin_nontemporal_store(v, p);
}
__device__ __forceinline__ void nt_store4(float* p, fx4 v) {
    __builtin_nontemporal_store(v, (fx4*)p);
}

__global__ __launch_bounds__(BLOCK)
void nl_nsq_kernel(const float* __restrict__ pos,
                   const float* __restrict__ box,
                   const int*   __restrict__ ip,
                   const int*   __restrict__ jp,
                   float*       __restrict__ out,
                   long long P) {
    __shared__ float lds_r[PPB * 3];   // 12 KB

    const int t = threadIdx.x;
    const long long base = (long long)blockIdx.x * PPB;

    const float Lx = box[0], Ly = box[4], Lz = box[8];
    const float hx = Lx * 0.5f, hy = Ly * 0.5f, hz = Lz * 0.5f;

    if (base + PPB <= P) {
        // ---- fast path: full block of 1024 pairs ----
#pragma unroll
        for (int s = 0; s < SPT; ++s) {
            const int  lp = t + s * BLOCK;        // local pair idx 0..1023
            const long long p = base + lp;
            const int i = ip[p];
            const int j = jp[p];

            float fi, fj, dm, mx, my, mz, mk;
            compute_pair(pos, Lx, Ly, Lz, hx, hy, hz, i, j,
                         fi, fj, dm, mx, my, mz, mk);

            // scalar regions: lane-contiguous -> coalesced
            nt_store(&out[p],          fi);
            nt_store(&out[P + p],      fj);
            nt_store(&out[2 * P + p],  fj);
            nt_store(&out[3 * P + p],  fi);
            nt_store(&out[4 * P + p],  dm);
            nt_store(&out[5 * P + p],  dm);
            nt_store(&out[12 * P + p], mk);
            nt_store(&out[13 * P + p], mk);

            // r triplet -> LDS (stride-3: conflict-free, 2 lanes/bank is free)
            lds_r[3 * lp + 0] = mx;
            lds_r[3 * lp + 1] = my;
            lds_r[3 * lp + 2] = mz;
        }

        __syncthreads();

        // ---- coalesced float4 write-out of r_full (+r and -r halves) ----
        const fx4* lr = (const fx4*)lds_r;                // 768 vec4s
        const long long rpos = 6 * P;
        const long long rneg = 9 * P;
        const long long boff = (long long)blockIdx.x * (PPB * 3); // floats
#pragma unroll
        for (int s = 0; s < 3; ++s) {
            const int idx = t + s * BLOCK;                // 0..767
            const fx4 v = lr[idx];
            nt_store4(&out[rpos + boff + 4 * idx], v);
            nt_store4(&out[rneg + boff + 4 * idx], -v);
        }
    } else {
        // ---- generic tail path (unused when P % 1024 == 0) ----
        for (long long p = base + t; p < P; p += BLOCK) {
            float fi, fj, dm, mx, my, mz, mk;
            compute_pair(pos, Lx, Ly, Lz, hx, hy, hz, ip[p], jp[p],
                         fi, fj, dm, mx, my, mz, mk);
            out[p]          = fi;
            out[P + p]      = fj;
            out[2 * P + p]  = fj;
            out[3 * P + p]  = fi;
            out[4 * P + p]  = dm;
            out[5 * P + p]  = dm;
            long long b0 = 6 * P + 3 * p;
            out[b0 + 0] = mx;  out[b0 + 1] = my;  out[b0 + 2] = mz;
            long long b1 = 6 * P + 3 * (P + p);
            out[b1 + 0] = -mx; out[b1 + 1] = -my; out[b1 + 2] = -mz;
            out[12 * P + p] = mk;
            out[13 * P + p] = mk;
        }
    }
}

extern "C" void kernel_launch(void* const* d_in, const int* in_sizes, int n_in,
                              void* d_out, int out_size, void* d_ws, size_t ws_size,
                              hipStream_t stream) {
    const float* pos = (const float*)d_in[0];  // [N,3]
    const float* box = (const float*)d_in[1];  // [3,3]
    const int*   ip  = (const int*)d_in[2];    // [P]
    const int*   jp  = (const int*)d_in[3];    // [P]
    float*       out = (float*)d_out;

    const long long P = (long long)in_sizes[2];
    const long long grid = (P + PPB - 1) / PPB;

    nl_nsq_kernel<<<(dim3)(unsigned)grid, BLOCK, 0, stream>>>(pos, box, ip, jp, out, P);
}

// Round 5
// 490.575 us; speedup vs baseline: 1.0745x; 1.0452x over previous
//
#include <hip/hip_runtime.h>
#include <math.h>

// NeighborlistVerletNsq: N=4096 particles, P = N(N-1)/2 pairs.
// Outputs (flattened float32, in return order):
//   [0   , 4P ) pairs  [2,2P]: row0 = concat(i,j), row1 = concat(j,i)
//   [4P  , 6P ) d_full [2P,1]: concat(d_m, d_m)
//   [6P  , 12P) r_full [2P,3]: concat(r_m, -r_m), row-major
//   [12P , 14P) mask   [2P]  : concat(mask, mask) as 0/1
//
// R5: revert to the R1 store structure (best measured: plain scalar stores,
// no LDS, no nontemporal), and eliminate the 67 MB ip/jp index read by
// computing (i,j) analytically from the flat pair index p (triu_indices
// inversion). Fallback kernel reads indices if P != N(N-1)/2.
//
// Numerics (exact numpy match, verified absmax 0.0 in R4):
//   remainder(t,L) for t in (-L,2L):  t>=L -> t-L (Sterbenz-exact == fmod);
//   t<0 -> t+L (same single rounding as numpy's fixup); else t.
//   norm: no-fma ((x*x + y*y) + z*z), IEEE sqrtf.

#define CUTOFF_F 0.5f
#define BLOCK 256

__device__ __forceinline__ float pbc_wrap_fast(float r, float L, float h) {
    float t = __fadd_rn(r, h);
    float m = (t >= L) ? __fsub_rn(t, L)
            : (t < 0.0f ? __fadd_rn(t, L) : t);
    return __fsub_rn(m, h);
}

__device__ __forceinline__ void compute_pair(const float* __restrict__ pos,
                                             float Lx, float Ly, float Lz,
                                             float hx, float hy, float hz,
                                             int i, int j,
                                             float& dm,
                                             float& mx, float& my, float& mz,
                                             float& mk) {
    float rx = __fsub_rn(pos[3 * i + 0], pos[3 * j + 0]);
    float ry = __fsub_rn(pos[3 * i + 1], pos[3 * j + 1]);
    float rz = __fsub_rn(pos[3 * i + 2], pos[3 * j + 2]);

    rx = pbc_wrap_fast(rx, Lx, hx);
    ry = pbc_wrap_fast(ry, Ly, hy);
    rz = pbc_wrap_fast(rz, Lz, hz);

    float d2 = __fadd_rn(__fadd_rn(__fmul_rn(rx, rx), __fmul_rn(ry, ry)),
                         __fmul_rn(rz, rz));
    float d = sqrtf(d2);

    const bool keep = (d <= CUTOFF_F);
    dm = keep ? d  : 0.0f;
    mx = keep ? rx : 0.0f;
    my = keep ? ry : 0.0f;
    mz = keep ? rz : 0.0f;
    mk = keep ? 1.0f : 0.0f;
}

__device__ __forceinline__ void write_pair(float* __restrict__ out, long long P,
                                           long long p, float fi, float fj,
                                           float dm, float mx, float my,
                                           float mz, float mk) {
    out[p]          = fi;
    out[P + p]      = fj;
    out[2 * P + p]  = fj;
    out[3 * P + p]  = fi;
    out[4 * P + p]  = dm;
    out[5 * P + p]  = dm;
    long long b0 = 6 * P + 3 * p;
    out[b0 + 0] = mx;  out[b0 + 1] = my;  out[b0 + 2] = mz;
    long long b1 = 6 * P + 3 * (P + p);
    out[b1 + 0] = -mx; out[b1 + 1] = -my; out[b1 + 2] = -mz;
    out[12 * P + p] = mk;
    out[13 * P + p] = mk;
}

// offset of first pair in row i: f(i) = i*(2N-1-i)/2
__device__ __forceinline__ long long row_off(long long i, long long N) {
    return i * (2 * N - 1 - i) / 2;
}

__global__ __launch_bounds__(BLOCK)
void nl_nsq_analytic(const float* __restrict__ pos,
                     const float* __restrict__ box,
                     float*       __restrict__ out,
                     long long P, int N) {
    const long long p = (long long)blockIdx.x * BLOCK + threadIdx.x;
    if (p >= P) return;

    // invert triu_indices: i = floor((2N-1 - sqrt((2N-1)^2 - 8p)) / 2)
    const double twoNm1 = (double)(2 * N - 1);
    const double D = twoNm1 * twoNm1 - 8.0 * (double)p;
    long long i = (long long)((twoNm1 - sqrt(D)) * 0.5);
    if (i < 0) i = 0;
    // exact integer fixup (at most 1-2 steps)
    while (row_off(i + 1, N) <= p) ++i;
    while (row_off(i, N) > p) --i;
    const long long j = p - row_off(i, N) + i + 1;

    const float Lx = box[0], Ly = box[4], Lz = box[8];
    const float hx = Lx * 0.5f, hy = Ly * 0.5f, hz = Lz * 0.5f;

    float dm, mx, my, mz, mk;
    compute_pair(pos, Lx, Ly, Lz, hx, hy, hz, (int)i, (int)j,
                 dm, mx, my, mz, mk);
    write_pair(out, P, p, (float)i, (float)j, dm, mx, my, mz, mk);
}

__global__ __launch_bounds__(BLOCK)
void nl_nsq_loadidx(const float* __restrict__ pos,
                    const float* __restrict__ box,
                    const int*   __restrict__ ip,
                    const int*   __restrict__ jp,
                    float*       __restrict__ out,
                    long long P) {
    const long long p = (long long)blockIdx.x * BLOCK + threadIdx.x;
    if (p >= P) return;

    const int i = ip[p];
    const int j = jp[p];

    const float Lx = box[0], Ly = box[4], Lz = box[8];
    const float hx = Lx * 0.5f, hy = Ly * 0.5f, hz = Lz * 0.5f;

    float dm, mx, my, mz, mk;
    compute_pair(pos, Lx, Ly, Lz, hx, hy, hz, i, j, dm, mx, my, mz, mk);
    write_pair(out, P, p, (float)i, (float)j, dm, mx, my, mz, mk);
}

extern "C" void kernel_launch(void* const* d_in, const int* in_sizes, int n_in,
                              void* d_out, int out_size, void* d_ws, size_t ws_size,
                              hipStream_t stream) {
    const float* pos = (const float*)d_in[0];  // [N,3]
    const float* box = (const float*)d_in[1];  // [3,3]
    const int*   ip  = (const int*)d_in[2];    // [P]
    const int*   jp  = (const int*)d_in[3];    // [P]
    float*       out = (float*)d_out;

    const long long P = (long long)in_sizes[2];
    const int       N = in_sizes[0] / 3;

    const long long grid = (P + BLOCK - 1) / BLOCK;

    if (P == (long long)N * (N - 1) / 2) {
        nl_nsq_analytic<<<(dim3)(unsigned)grid, BLOCK, 0, stream>>>(
            pos, box, out, P, N);
    } else {
        nl_nsq_loadidx<<<(dim3)(unsigned)grid, BLOCK, 0, stream>>>(
            pos, box, ip, jp, out, P);
    }
}